// Round 7
// baseline (84.246 us; speedup 1.0000x reference)
//
#include <hip/hip_runtime.h>

typedef float v2f    __attribute__((ext_vector_type(2)));
typedef float f32x16 __attribute__((ext_vector_type(16)));
typedef short short8 __attribute__((ext_vector_type(8)));

#define MPTS 8192          // pc points per batch
#define NVERT 8192         // mesh vertices per batch (256 tiles of 32)
#define NTILE (NVERT/32)   // 256 vertex tiles per batch
#define NCHUNK 2           // vertex chunks (parallelism for minpart)
#define TPB 256

// bf16 hi/lo split helpers (truncation — pure bit ops).
static __device__ __forceinline__ unsigned short bhi(float f) {
    return (unsigned short)(__float_as_uint(f) >> 16);
}
static __device__ __forceinline__ float bf2f(unsigned short h) {
    return __uint_as_float(((unsigned int)h) << 16);
}

// Kernel 0: pack vertices into MFMA B-fragment order (bf16 hi/lo + |v|^2).
// B k-layout (K=16): [vhx,vhy,vhz, vhx,vhy,vhz, vlx,vly | vlz, wh, wl, 0...]
// Fragment-linear storage: ushort index = ((b*NTILE + tile)*64 + lane)*8 + j,
// vertex v -> lanes c=v&31 (k=0..7) and c+32 (k=8..15).
__global__ __launch_bounds__(TPB) void prep_kernel(
        const float* __restrict__ vert,      // [B,3,NVERT]
        unsigned short* __restrict__ bfrag)  // [B,NTILE,64,8]
{
    const int idx = blockIdx.x * TPB + threadIdx.x;
    const int b = idx >> 13, v = idx & (NVERT - 1);
    const float* vb = vert + (size_t)b * 3 * NVERT;
    const float x = vb[v], y = vb[v + NVERT], z = vb[v + 2 * NVERT];
    const unsigned short hx = bhi(x), hy = bhi(y), hz = bhi(z);
    const unsigned short lx = bhi(x - bf2f(hx));
    const unsigned short ly = bhi(y - bf2f(hy));
    const unsigned short lz = bhi(z - bf2f(hz));
    const float w = fmaf(x, x, fmaf(y, y, z * z));
    const unsigned short hw = bhi(w);
    const unsigned short lw = bhi(w - bf2f(hw));

    const int tile = v >> 5, c = v & 31;
    unsigned short* base = bfrag + ((size_t)b * NTILE + tile) * 512;
    short8 g0 = {(short)hx, (short)hy, (short)hz,
                 (short)hx, (short)hy, (short)hz, (short)lx, (short)ly};
    short8 g1 = {(short)lz, (short)hw, (short)lw, 0, 0, 0, 0, 0};
    *(short8*)(base + c * 8)        = g0;
    *(short8*)(base + (c + 32) * 8) = g1;
}

// Kernel 1: MFMA minpart. One wave = 32 points x one 4096-vertex chunk.
// Each 32x32x16 bf16 MFMA yields t[m][n] = |v_n|^2 - 2 p_m . v_n for a
// 32x32 pair tile; fold into 16 running mins/lane, shfl-reduce over cols.
// A k-layout: [ahx,ahy,ahz, alx,aly,alz, ahx,ahy | ahz, 1, 1, 0...], a=-2p.
__global__ __launch_bounds__(TPB, 2) void minpart_kernel(
        const unsigned short* __restrict__ bfrag,  // [B,NTILE,64,8]
        const float* __restrict__ pc,              // [B,3,MPTS]
        float* __restrict__ partial)               // [B,NCHUNK,MPTS]
{
    const int b = blockIdx.z, chunk = blockIdx.y;
    const int tid = threadIdx.x;
    const int wave = tid >> 6, l = tid & 63;
    const int half = l >> 5, lm = l & 31;
    const int strip = blockIdx.x * 4 + wave;        // 0..255 (32-point strips)
    const int pm = strip * 32 + lm;

    // Build the (constant) A fragment for this lane: a = -2p, hi/lo split.
    const float* pcb = pc + (size_t)b * 3 * MPTS;
    const float ax = -2.0f * pcb[pm];
    const float ay = -2.0f * pcb[pm + MPTS];
    const float az = -2.0f * pcb[pm + 2 * MPTS];
    const unsigned short hx = bhi(ax), hy = bhi(ay), hz = bhi(az);
    const unsigned short lx = bhi(ax - bf2f(hx));
    const unsigned short ly = bhi(ay - bf2f(hy));
    const unsigned short lz = bhi(az - bf2f(hz));
    const unsigned short ONE = 0x3F80;              // bf16(1.0)

    short8 A;
    A[0] = half ? (short)hz : (short)hx;
    A[1] = half ? (short)ONE : (short)hy;
    A[2] = half ? (short)ONE : (short)hz;
    A[3] = half ? (short)0   : (short)lx;
    A[4] = half ? (short)0   : (short)ly;
    A[5] = half ? (short)0   : (short)lz;
    A[6] = half ? (short)0   : (short)hx;
    A[7] = half ? (short)0   : (short)hy;

    // B fragments: coalesced 16B/lane per tile, L2-resident.
    const unsigned short* bp =
        bfrag + ((size_t)b * NTILE + chunk * (NTILE / NCHUNK)) * 512 + l * 8;

    f32x16 run;
    #pragma unroll
    for (int i = 0; i < 16; ++i) run[i] = 1e30f;
    const f32x16 zero = {};

    #pragma unroll 4
    for (int j = 0; j < NTILE / NCHUNK; ++j) {
        const short8 bv = *(const short8*)(bp + (size_t)j * 512);
        const f32x16 d = __builtin_amdgcn_mfma_f32_32x32x16_bf16(A, bv, zero, 0, 0, 0);
        #pragma unroll
        for (int i = 0; i < 16; ++i) run[i] = fminf(run[i], d[i]);
    }

    // Min over the 32 cols (vertices) held across lanes of each half-wave.
    #pragma unroll
    for (int m = 16; m; m >>= 1) {
        #pragma unroll
        for (int i = 0; i < 16; ++i)
            run[i] = fminf(run[i], __shfl_xor(run[i], m));
    }

    // C/D layout (verified): col=lane&31, row=(r&3)+8*(r>>2)+4*half.
    if (lm == 0) {
        float* po = partial + ((size_t)b * NCHUNK + chunk) * MPTS + strip * 32;
        #pragma unroll
        for (int r = 0; r < 16; ++r)
            po[(r & 3) + 8 * (r >> 2) + 4 * half] = run[r];
    }
}

// Kernel 2: fold NCHUNK planes, add |p|^2, mask all-zero columns, partials.
__global__ __launch_bounds__(64) void reduce_kernel(
        const float* __restrict__ pc,
        const float* __restrict__ partial,
        v2f* __restrict__ part)            // [B*32]
{
    const int b = blockIdx.x >> 5, sl = blockIdx.x & 31;
    const int tid = threadIdx.x;
    const int m = sl * 256 + tid * 4;
    const float* pcb = pc + (size_t)b * 3 * MPTS;
    const float* pb  = partial + (size_t)b * NCHUNK * MPTS;

    float4 t = *(const float4*)(pb + m);
    #pragma unroll
    for (int c = 1; c < NCHUNK; ++c) {
        const float4 u = *(const float4*)(pb + (size_t)c * MPTS + m);
        t.x = fminf(t.x, u.x); t.y = fminf(t.y, u.y);
        t.z = fminf(t.z, u.z); t.w = fminf(t.w, u.w);
    }
    const float4 x = *(const float4*)(pcb + m);
    const float4 y = *(const float4*)(pcb + MPTS + m);
    const float4 z = *(const float4*)(pcb + 2 * MPTS + m);

    float sum = 0.0f, cnt = 0.0f;
    {
        const float xs[4] = {x.x, x.y, x.z, x.w};
        const float ys[4] = {y.x, y.y, y.z, y.w};
        const float zs[4] = {z.x, z.y, z.z, z.w};
        const float ts[4] = {t.x, t.y, t.z, t.w};
        #pragma unroll
        for (int i = 0; i < 4; ++i) {
            const float d2 = fmaf(xs[i], xs[i], fmaf(ys[i], ys[i],
                             fmaf(zs[i], zs[i], ts[i])));
            if (!(xs[i] == 0.0f && ys[i] == 0.0f && zs[i] == 0.0f)) {
                sum += d2; cnt += 1.0f;
            }
        }
    }
    #pragma unroll
    for (int off = 32; off; off >>= 1) {
        sum += __shfl_down(sum, off);
        cnt += __shfl_down(cnt, off);
    }
    if (tid == 0) part[blockIdx.x] = (v2f){sum, cnt};
}

// Kernel 3: fold B*32 (sum,cnt) partials -> per-item means -> batch mean.
__global__ __launch_bounds__(128) void final_kernel(
        const v2f* __restrict__ part, float* __restrict__ out, int B)
{
    __shared__ float ss[128], sc[128];
    const int t = threadIdx.x;
    v2f p = (v2f){0.0f, 0.0f};
    if (t < B * 32) p = part[t];
    ss[t] = p.x; sc[t] = p.y;
    __syncthreads();
    if (t == 0) {
        float acc = 0.0f;
        for (int b = 0; b < B; ++b) {
            float s = 0.0f, c = 0.0f;
            for (int i = 0; i < 32; ++i) { s += ss[b * 32 + i]; c += sc[b * 32 + i]; }
            acc += s / c;
        }
        out[0] = acc / (float)B;
    }
}

extern "C" void kernel_launch(void* const* d_in, const int* in_sizes, int n_in,
                              void* d_out, int out_size, void* d_ws, size_t ws_size,
                              hipStream_t stream) {
    const float* vert = (const float*)d_in[0];  // [B,3,128,64]
    const float* pc   = (const float*)d_in[1];  // [B,3,8192]
    float* out        = (float*)d_out;
    const int B = in_sizes[0] / (3 * NVERT);

    unsigned short* bfrag = (unsigned short*)d_ws;                 // [B,256,64,8] = 1 MB (B=4)
    float* partial = (float*)((char*)d_ws + (size_t)B * NTILE * 512 * sizeof(unsigned short));
    v2f* part = (v2f*)(partial + (size_t)B * NCHUNK * MPTS);       // [B*32]

    prep_kernel<<<B * NVERT / TPB, TPB, 0, stream>>>(vert, bfrag);
    dim3 grid(NVERT / 32 / 4, NCHUNK, B);   // 64 x 2 x B blocks of 4 waves
    minpart_kernel<<<grid, TPB, 0, stream>>>(bfrag, pc, partial);
    reduce_kernel<<<B * 32, 64, 0, stream>>>(pc, partial, part);
    final_kernel<<<1, 128, 0, stream>>>(part, out, B);
}

// Round 8
// 79.818 us; speedup vs baseline: 1.0555x; 1.0555x over previous
//
#include <hip/hip_runtime.h>

typedef float v2f    __attribute__((ext_vector_type(2)));
typedef float f32x16 __attribute__((ext_vector_type(16)));
typedef short short8 __attribute__((ext_vector_type(8)));

#define MPTS 8192          // pc points per batch
#define NVERT 8192         // mesh vertices per batch (256 tiles of 32)
#define NTILE (NVERT/32)   // 256 vertex tiles per batch
#define NCHUNK 16          // vertex chunks (occupancy for minpart)
#define TPC (NTILE/NCHUNK) // 16 vertex tiles per chunk
#define NSTRIP 4           // point strips (B-fragments) per wave
#define TPB 256

// bf16 hi/lo split helpers (truncation — pure bit ops).
static __device__ __forceinline__ unsigned short bhi(float f) {
    return (unsigned short)(__float_as_uint(f) >> 16);
}
static __device__ __forceinline__ float bf2f(unsigned short h) {
    return __uint_as_float(((unsigned int)h) << 16);
}

// Kernel 0: pack vertices into MFMA vert-fragment order (bf16 hi/lo + |v|^2).
// Fragment k-layout (K=16): [vhx,vhy,vhz, vhx,vhy,vhz, vlx,vly | vlz, wh, wl, 0...]
// Lane l holds vert row = l&31, k = (l>>5)*8 + j. Storage fragment-linear:
// ushort index = ((b*NTILE + tile)*64 + lane)*8 + j.
__global__ __launch_bounds__(TPB) void prep_kernel(
        const float* __restrict__ vert,      // [B,3,NVERT]
        unsigned short* __restrict__ afrag)  // [B,NTILE,64,8]
{
    const int idx = blockIdx.x * TPB + threadIdx.x;
    const int b = idx >> 13, v = idx & (NVERT - 1);
    const float* vb = vert + (size_t)b * 3 * NVERT;
    const float x = vb[v], y = vb[v + NVERT], z = vb[v + 2 * NVERT];
    const unsigned short hx = bhi(x), hy = bhi(y), hz = bhi(z);
    const unsigned short lx = bhi(x - bf2f(hx));
    const unsigned short ly = bhi(y - bf2f(hy));
    const unsigned short lz = bhi(z - bf2f(hz));
    const float w = fmaf(x, x, fmaf(y, y, z * z));
    const unsigned short hw = bhi(w);
    const unsigned short lw = bhi(w - bf2f(hw));

    const int tile = v >> 5, c = v & 31;
    unsigned short* base = afrag + ((size_t)b * NTILE + tile) * 512;
    short8 g0 = {(short)hx, (short)hy, (short)hz,
                 (short)hx, (short)hy, (short)hz, (short)lx, (short)ly};
    short8 g1 = {(short)lz, (short)hw, (short)lw, 0, 0, 0, 0, 0};
    *(short8*)(base + c * 8)        = g0;   // k = 0..7 half
    *(short8*)(base + (c + 32) * 8) = g1;   // k = 8..15 half
}

// Kernel 1: MFMA minpart, verts-on-rows / points-on-cols.
// One wave = 4 point strips (128 points) x one TPC-tile vertex chunk.
// Per tile: 1 coalesced 16B/lane A-load (reused 4x) + 4 MFMA; lane folds its
// 16 vert-rows in-register, epilogue = 15 v_min + 1 shfl_xor(32) per strip.
__global__ __launch_bounds__(TPB, 4) void minpart_kernel(
        const unsigned short* __restrict__ afrag,  // [B,NTILE,64,8]
        const float* __restrict__ pc,              // [B,3,MPTS]
        float* __restrict__ partial)               // [B,NCHUNK,MPTS]
{
    const int b = blockIdx.z, chunk = blockIdx.y;
    const int tid = threadIdx.x;
    const int wave = tid >> 6, l = tid & 63;
    const int half = l >> 5, lm = l & 31;
    const int group = blockIdx.x * 4 + wave;        // 0..63 (128-point groups)
    const unsigned short ONE = 0x3F80;              // bf16(1.0)

    // Build the 4 point B-fragments (a = -2p, bf16 hi/lo split).
    const float* pcb = pc + (size_t)b * 3 * MPTS;
    short8 Bf[NSTRIP];
    #pragma unroll
    for (int q = 0; q < NSTRIP; ++q) {
        const int pm = group * 128 + q * 32 + lm;
        const float ax = -2.0f * pcb[pm];
        const float ay = -2.0f * pcb[pm + MPTS];
        const float az = -2.0f * pcb[pm + 2 * MPTS];
        const unsigned short hx = bhi(ax), hy = bhi(ay), hz = bhi(az);
        const unsigned short lx = bhi(ax - bf2f(hx));
        const unsigned short ly = bhi(ay - bf2f(hy));
        const unsigned short lz = bhi(az - bf2f(hz));
        Bf[q][0] = half ? (short)hz : (short)hx;
        Bf[q][1] = half ? (short)ONE : (short)hy;
        Bf[q][2] = half ? (short)ONE : (short)hz;
        Bf[q][3] = half ? (short)0   : (short)lx;
        Bf[q][4] = half ? (short)0   : (short)ly;
        Bf[q][5] = half ? (short)0   : (short)lz;
        Bf[q][6] = half ? (short)0   : (short)hx;
        Bf[q][7] = half ? (short)0   : (short)hy;
    }

    // Vertex A-fragments for this chunk: 16B/lane per tile, L2-resident.
    const unsigned short* ap =
        afrag + ((size_t)b * NTILE + chunk * TPC) * 512 + l * 8;

    f32x16 run[NSTRIP];
    #pragma unroll
    for (int q = 0; q < NSTRIP; ++q)
        #pragma unroll
        for (int i = 0; i < 16; ++i) run[q][i] = 1e30f;
    const f32x16 zero = {};

    #pragma unroll 2
    for (int j = 0; j < TPC; ++j) {
        const short8 Av = *(const short8*)(ap + (size_t)j * 512);
        #pragma unroll
        for (int q = 0; q < NSTRIP; ++q) {
            const f32x16 d = __builtin_amdgcn_mfma_f32_32x32x16_bf16(Av, Bf[q], zero, 0, 0, 0);
            #pragma unroll
            for (int i = 0; i < 16; ++i) run[q][i] = fminf(run[q][i], d[i]);
        }
    }

    // In-lane fold over this lane's 16 vert rows, then merge the other half's
    // 16 rows via one xor-32 shuffle. Lane's col = its point (lm).
    float* po = partial + ((size_t)b * NCHUNK + chunk) * MPTS + group * 128;
    #pragma unroll
    for (int q = 0; q < NSTRIP; ++q) {
        float m01 = fminf(run[q][0], run[q][1]), m23 = fminf(run[q][2], run[q][3]);
        float m45 = fminf(run[q][4], run[q][5]), m67 = fminf(run[q][6], run[q][7]);
        float m89 = fminf(run[q][8], run[q][9]), mab = fminf(run[q][10], run[q][11]);
        float mcd = fminf(run[q][12], run[q][13]), mef = fminf(run[q][14], run[q][15]);
        float m = fminf(fminf(fminf(m01, m23), fminf(m45, m67)),
                        fminf(fminf(m89, mab), fminf(mcd, mef)));
        m = fminf(m, __shfl_xor(m, 32));
        if (half == 0) po[q * 32 + lm] = m;
    }
}

// Kernel 2: fold NCHUNK planes, add |p|^2, mask all-zero columns, partials.
__global__ __launch_bounds__(64) void reduce_kernel(
        const float* __restrict__ pc,
        const float* __restrict__ partial,
        v2f* __restrict__ part)            // [B*32]
{
    const int b = blockIdx.x >> 5, sl = blockIdx.x & 31;
    const int tid = threadIdx.x;
    const int m = sl * 256 + tid * 4;
    const float* pcb = pc + (size_t)b * 3 * MPTS;
    const float* pb  = partial + (size_t)b * NCHUNK * MPTS;

    float4 t = *(const float4*)(pb + m);
    #pragma unroll
    for (int c = 1; c < NCHUNK; ++c) {
        const float4 u = *(const float4*)(pb + (size_t)c * MPTS + m);
        t.x = fminf(t.x, u.x); t.y = fminf(t.y, u.y);
        t.z = fminf(t.z, u.z); t.w = fminf(t.w, u.w);
    }
    const float4 x = *(const float4*)(pcb + m);
    const float4 y = *(const float4*)(pcb + MPTS + m);
    const float4 z = *(const float4*)(pcb + 2 * MPTS + m);

    float sum = 0.0f, cnt = 0.0f;
    {
        const float xs[4] = {x.x, x.y, x.z, x.w};
        const float ys[4] = {y.x, y.y, y.z, y.w};
        const float zs[4] = {z.x, z.y, z.z, z.w};
        const float ts[4] = {t.x, t.y, t.z, t.w};
        #pragma unroll
        for (int i = 0; i < 4; ++i) {
            const float d2 = fmaf(xs[i], xs[i], fmaf(ys[i], ys[i],
                             fmaf(zs[i], zs[i], ts[i])));
            if (!(xs[i] == 0.0f && ys[i] == 0.0f && zs[i] == 0.0f)) {
                sum += d2; cnt += 1.0f;
            }
        }
    }
    #pragma unroll
    for (int off = 32; off; off >>= 1) {
        sum += __shfl_down(sum, off);
        cnt += __shfl_down(cnt, off);
    }
    if (tid == 0) part[blockIdx.x] = (v2f){sum, cnt};
}

// Kernel 3: fold B*32 (sum,cnt) partials -> per-item means -> batch mean.
__global__ __launch_bounds__(128) void final_kernel(
        const v2f* __restrict__ part, float* __restrict__ out, int B)
{
    __shared__ float ss[128], sc[128];
    const int t = threadIdx.x;
    v2f p = (v2f){0.0f, 0.0f};
    if (t < B * 32) p = part[t];
    ss[t] = p.x; sc[t] = p.y;
    __syncthreads();
    if (t == 0) {
        float acc = 0.0f;
        for (int b = 0; b < B; ++b) {
            float s = 0.0f, c = 0.0f;
            for (int i = 0; i < 32; ++i) { s += ss[b * 32 + i]; c += sc[b * 32 + i]; }
            acc += s / c;
        }
        out[0] = acc / (float)B;
    }
}

extern "C" void kernel_launch(void* const* d_in, const int* in_sizes, int n_in,
                              void* d_out, int out_size, void* d_ws, size_t ws_size,
                              hipStream_t stream) {
    const float* vert = (const float*)d_in[0];  // [B,3,128,64]
    const float* pc   = (const float*)d_in[1];  // [B,3,8192]
    float* out        = (float*)d_out;
    const int B = in_sizes[0] / (3 * NVERT);

    unsigned short* afrag = (unsigned short*)d_ws;                 // [B,256,64,8] = 1 MB (B=4)
    float* partial = (float*)((char*)d_ws + (size_t)B * NTILE * 512 * sizeof(unsigned short));
    v2f* part = (v2f*)(partial + (size_t)B * NCHUNK * MPTS);       // [B*32]

    prep_kernel<<<B * NVERT / TPB, TPB, 0, stream>>>(vert, afrag);
    dim3 grid(64 / NSTRIP, NCHUNK, B);   // 16 x 16 x B = 1024 blocks
    minpart_kernel<<<grid, TPB, 0, stream>>>(afrag, pc, partial);
    reduce_kernel<<<B * 32, 64, 0, stream>>>(pc, partial, part);
    final_kernel<<<1, 128, 0, stream>>>(part, out, B);
}